// Round 10
// baseline (635.212 us; speedup 1.0000x reference)
//
#include <hip/hip_runtime.h>
#include <math.h>

#define NN 50000
#define NE 800000
#define IND 256
#define ED 64
#define EMB 128
#define NH 8
#define HD 16

typedef short bf16x8 __attribute__((ext_vector_type(8)));
typedef float f32x4 __attribute__((ext_vector_type(4)));

#define NPT  (NN / 16)                  // 3125 proj tiles
#define NPB  ((NPT + 3) / 4)            // 782 proj blocks
#define NHIST ((NE + 255) / 256)        // 3125 hist blocks
#define NB   ((NN + 511) / 512)         // 98 scan blocks

__device__ __forceinline__ unsigned short rne16(float f) {
    unsigned u = __float_as_uint(f);
    unsigned r = u + 0x7FFFu + ((u >> 16) & 1u);
    return (unsigned short)(r >> 16);
}

__device__ __forceinline__ float bf2f(short s) {
    return __uint_as_float(((unsigned)(unsigned short)s) << 16);
}

__device__ __forceinline__ float mishf(float v) {
    float t = __expf(fminf(v, 20.f));
    float u = 1.f + t;
    u = u * u;
    return v * (u - 1.f) * __builtin_amdgcn_rcpf(u + 1.f);
}

// ------- fused: MFMA node projection + rcv histogram -----------------------
__global__ __launch_bounds__(256) void k_proj_hist(
    const float* __restrict__ X, const float* __restrict__ W,
    const float* __restrict__ b, short* __restrict__ hbf,
    const int* __restrict__ rcv, int* __restrict__ cnt) {
    if (blockIdx.x >= NPB) {            // histogram part
        int e = (blockIdx.x - NPB) * 256 + threadIdx.x;
        if (e < NE) atomicAdd(&cnt[rcv[e]], 1);
        return;
    }
    __shared__ short BHs[IND * EMB];    // 64 KB bf16 fragment tile
    for (int idx = threadIdx.x * 4; idx < IND * EMB; idx += 256 * 4) {
        float4 wv = *(const float4*)&W[idx];
        int k = idx >> 7;
        int col = idx & 127;
        int kk8 = k >> 5, qq = (k & 31) >> 3, j = k & 7;
        float wf[4] = {wv.x, wv.y, wv.z, wv.w};
        #pragma unroll
        for (int i = 0; i < 4; ++i) {
            int cc = (col + i) & 7, lc = (col + i) >> 3;
            int lane = (qq << 4) | lc;
            BHs[(((cc << 3) | kk8) * 64 + lane) * 8 + j] = (short)rne16(wf[i]);
        }
    }
    __syncthreads();

    const int l = threadIdx.x & 63;
    const int lanecol = l & 15;
    const int q = l >> 4;
    const int wid = (blockIdx.x << 2) + (threadIdx.x >> 6);
    const int nW = NPB << 2;

    float4 bv0 = *(const float4*)&b[lanecol * 8];
    float4 bv1 = *(const float4*)&b[lanecol * 8 + 4];
    float wb[8] = {bv0.x, bv0.y, bv0.z, bv0.w, bv1.x, bv1.y, bv1.z, bv1.w};

    for (int tIdx = wid; tIdx < NPT; tIdx += nW) {
        const int n0 = tIdx * 16;
        f32x4 acc[8];
        #pragma unroll
        for (int c = 0; c < 8; ++c) acc[c] = (f32x4){0.f, 0.f, 0.f, 0.f};
        #pragma unroll
        for (int kk8 = 0; kk8 < 8; ++kk8) {
            const float* ar = X + (size_t)(n0 + lanecol) * IND + kk8 * 32 + q * 8;
            float4 a0 = *(const float4*)ar;
            float4 a1 = *(const float4*)(ar + 4);
            float faf[8] = {a0.x, a0.y, a0.z, a0.w, a1.x, a1.y, a1.z, a1.w};
            bf16x8 ahi;
            #pragma unroll
            for (int j = 0; j < 8; ++j) ahi[j] = (short)rne16(faf[j]);
            #pragma unroll
            for (int c = 0; c < 8; ++c) {
                bf16x8 bh = *(bf16x8*)&BHs[(((c << 3) | kk8) * 64 + l) * 8];
                acc[c] = __builtin_amdgcn_mfma_f32_16x16x32_bf16(ahi, bh, acc[c], 0, 0, 0);
            }
        }
        #pragma unroll
        for (int r = 0; r < 4; ++r) {
            const int node = n0 + (q << 2) + r;
            bf16x8 ov;
            #pragma unroll
            for (int c = 0; c < 8; ++c) ov[c] = (short)rne16(acc[c][r] + wb[c]);
            *(bf16x8*)(hbf + (size_t)node * EMB + lanecol * 8) = ov;
        }
    }
}

// ---------------- CSR build: per-block scan, merged fixup ------------------
__global__ __launch_bounds__(512) void k_part(const int* __restrict__ cnt,
                                              int* __restrict__ rowptr,
                                              int* __restrict__ part) {
    __shared__ int sm[512];
    const int t = threadIdx.x;
    const int idx = blockIdx.x * 512 + t;
    int v = (idx < NN) ? cnt[idx] : 0;
    sm[t] = v;
    __syncthreads();
    #pragma unroll
    for (int off = 1; off < 512; off <<= 1) {
        int y = (t >= off) ? sm[t - off] : 0;
        __syncthreads();
        sm[t] += y;
        __syncthreads();
    }
    if (idx < NN) rowptr[idx] = sm[t] - v;
    if (t == 511) part[blockIdx.x] = sm[511];
}

__global__ __launch_bounds__(512) void k_fix2(const int* __restrict__ part,
                                              int* __restrict__ rowptr,
                                              int* __restrict__ cursor) {
    __shared__ int sm[128];
    const int t = threadIdx.x;
    if (t < 128) sm[t] = (t < NB) ? part[t] : 0;
    __syncthreads();
    #pragma unroll
    for (int off = 1; off < 128; off <<= 1) {
        int y = 0;
        if (t < 128 && t >= off) y = sm[t - off];
        __syncthreads();
        if (t < 128) sm[t] += y;
        __syncthreads();
    }
    const int boff = (blockIdx.x > 0) ? sm[blockIdx.x - 1] : 0;
    const int idx = blockIdx.x * 512 + t;
    if (idx < NN) {
        int r = rowptr[idx] + boff;
        rowptr[idx] = r;
        cursor[idx] = r;
    }
    if (blockIdx.x == 0 && t == 0) rowptr[NN] = NE;
}

// ---------- fused edge pass: bf16 MFMA + gather + mish + exp + bucket ------
// VGPR-lean: target 64 VGPR -> 8 waves/SIMD (the m69 occupancy step).
__global__ __launch_bounds__(256, 8) void k_edge_attn(
    const float* __restrict__ EF, const float* __restrict__ We,
    const float* __restrict__ Web, const float* __restrict__ Av,
    const short* __restrict__ hbf, const int* __restrict__ snd,
    const int* __restrict__ rcv, int* __restrict__ cursor,
    int* __restrict__ csr_snd, float* __restrict__ ex_csr) {
    __shared__ short BHs[ED * EMB];     // 16 KB bf16 fragment tile
    __shared__ float2 WA[144];          // (Web, Av) pairs, stride-9 padded
    for (int idx = threadIdx.x * 4; idx < ED * EMB; idx += 256 * 4) {
        float4 wv = *(const float4*)&We[idx];
        int k = idx >> 7;
        int col = idx & 127;
        int kk = k >> 5, qq = (k & 31) >> 3, j = k & 7;
        float wf[4] = {wv.x, wv.y, wv.z, wv.w};
        #pragma unroll
        for (int i = 0; i < 4; ++i) {
            int cc = (col + i) & 7, lc = (col + i) >> 3;
            int lane = (qq << 4) | lc;
            BHs[(((cc << 1) | kk) * 64 + lane) * 8 + j] = (short)rne16(wf[i]);
        }
    }
    if (threadIdx.x < 128) {
        int c = threadIdx.x & 7, lc = threadIdx.x >> 3;
        WA[lc * 9 + c] = make_float2(Web[threadIdx.x], Av[threadIdx.x]);
    }
    __syncthreads();

    const int l = threadIdx.x & 63;
    const int lanecol = l & 15;
    const int q = l >> 4;
    const int wid = (blockIdx.x << 2) + (threadIdx.x >> 6);
    const int nW = gridDim.x << 2;
    const int NT = NE / 16;

    for (int tIdx = wid; tIdx < NT; tIdx += nW) {
        const int e0 = tIdx * 16;
        const float* ar = EF + (size_t)(e0 + lanecol) * ED + q * 8;
        // convert-on-the-fly: no fa[16] array
        bf16x8 ahi0, ahi1;
        {
            float4 a0 = *(const float4*)ar;
            float4 a1 = *(const float4*)(ar + 4);
            ahi0[0] = (short)rne16(a0.x); ahi0[1] = (short)rne16(a0.y);
            ahi0[2] = (short)rne16(a0.z); ahi0[3] = (short)rne16(a0.w);
            ahi0[4] = (short)rne16(a1.x); ahi0[5] = (short)rne16(a1.y);
            ahi0[6] = (short)rne16(a1.z); ahi0[7] = (short)rne16(a1.w);
        }
        {
            float4 a2 = *(const float4*)(ar + 32);
            float4 a3 = *(const float4*)(ar + 36);
            ahi1[0] = (short)rne16(a2.x); ahi1[1] = (short)rne16(a2.y);
            ahi1[2] = (short)rne16(a2.z); ahi1[3] = (short)rne16(a2.w);
            ahi1[4] = (short)rne16(a3.x); ahi1[5] = (short)rne16(a3.y);
            ahi1[6] = (short)rne16(a3.z); ahi1[7] = (short)rne16(a3.w);
        }
        f32x4 acc[8];
        #pragma unroll
        for (int c = 0; c < 8; ++c) acc[c] = (f32x4){0.f, 0.f, 0.f, 0.f};
        #pragma unroll
        for (int c = 0; c < 8; ++c) {
            bf16x8 b0 = *(bf16x8*)&BHs[(((c << 1) | 0) * 64 + l) * 8];
            acc[c] = __builtin_amdgcn_mfma_f32_16x16x32_bf16(ahi0, b0, acc[c], 0, 0, 0);
            bf16x8 b1 = *(bf16x8*)&BHs[(((c << 1) | 1) * 64 + l) * 8];
            acc[c] = __builtin_amdgcn_mfma_f32_16x16x32_bf16(ahi1, b1, acc[c], 0, 0, 0);
        }
        #pragma unroll
        for (int r = 0; r < 4; ++r) {
            const int e = e0 + (q << 2) + r;
            const int s = snd[e], rn = rcv[e];
            bf16x8 hsv8 = *(const bf16x8*)(hbf + (size_t)s * EMB + lanecol * 8);
            bf16x8 hrv8 = *(const bf16x8*)(hbf + (size_t)rn * EMB + lanecol * 8);
            float pp = 0.f;
            #pragma unroll
            for (int c = 0; c < 8; ++c) {
                float2 wa = WA[lanecol * 9 + c];
                float v = acc[c][r] + wa.x + bf2f(hsv8[c]) + bf2f(hrv8[c]);
                pp = fmaf(mishf(v), wa.y, pp);
            }
            pp += __shfl_xor(pp, 1, 16);
            int pos = 0;
            if (lanecol == 0) pos = atomicAdd(&cursor[rn], 1);
            pos = __shfl(pos, l & 48, 64);
            if (lanecol == 0) csr_snd[pos] = s;
            if ((lanecol & 1) == 0)
                ex_csr[(size_t)pos * NH + (lanecol >> 1)] = __expf(pp);
        }
    }
}

// --------- segmented aggregation: bf16 h, lane owns cols 2l,2l+1 -----------
__global__ __launch_bounds__(256) void k_agg(
    const short* __restrict__ hbf, const int* __restrict__ csr_snd,
    const float* __restrict__ ex_csr, const int* __restrict__ rowptr,
    float* __restrict__ out) {
    const int l = threadIdx.x & 63;
    const int node = blockIdx.x * 4 + (threadIdx.x >> 6);
    if (node >= NN) return;
    const int beg = rowptr[node], end = rowptr[node + 1];
    const int h = l >> 3;
    float a0 = 0.f, a1 = 0.f, den = 0.f;
    int j = beg;
    for (; j + 4 <= end; j += 4) {
        int s[4];
        float ex[4];
        unsigned hv[4];
        #pragma unroll
        for (int i = 0; i < 4; ++i) s[i] = csr_snd[j + i];
        #pragma unroll
        for (int i = 0; i < 4; ++i) ex[i] = ex_csr[(size_t)(j + i) * NH + h];
        #pragma unroll
        for (int i = 0; i < 4; ++i)
            hv[i] = *(const unsigned*)(hbf + (size_t)s[i] * EMB + 2 * l);
        #pragma unroll
        for (int i = 0; i < 4; ++i) {
            a0 = fmaf(ex[i], bf2f((short)(hv[i] & 0xFFFF)), a0);
            a1 = fmaf(ex[i], bf2f((short)(hv[i] >> 16)), a1);
            den += ex[i];
        }
    }
    for (; j < end; ++j) {
        float ex = ex_csr[(size_t)j * NH + h];
        unsigned hv = *(const unsigned*)(hbf + (size_t)csr_snd[j] * EMB + 2 * l);
        a0 = fmaf(ex, bf2f((short)(hv & 0xFFFF)), a0);
        a1 = fmaf(ex, bf2f((short)(hv >> 16)), a1);
        den += ex;
    }
    float rd = (end > beg) ? __builtin_amdgcn_rcpf(den) : 0.f;
    float2 o;
    o.x = a0 * rd;
    o.y = a1 * rd;
    *(float2*)&out[(size_t)node * EMB + 2 * l] = o;
}

extern "C" void kernel_launch(void* const* d_in, const int* in_sizes, int n_in,
                              void* d_out, int out_size, void* d_ws, size_t ws_size,
                              hipStream_t stream) {
    const float* X   = (const float*)d_in[0];
    const float* EF  = (const float*)d_in[1];
    const float* W   = (const float*)d_in[2];
    const float* Wb  = (const float*)d_in[3];
    const float* We  = (const float*)d_in[4];
    const float* Web = (const float*)d_in[5];
    const float* Av  = (const float*)d_in[6];
    const int* snd   = (const int*)d_in[7];
    const int* rcv   = (const int*)d_in[8];
    float* out = (float*)d_out;

    char* ws = (char*)d_ws;
    size_t off = 0;
    float* ex_csr = (float*)(ws + off); off += (size_t)NE * NH * 4;    // 25.6 MB
    int* csr_snd  = (int*)(ws + off);   off += (size_t)NE * 4;         // 3.2 MB
    int* rowptr   = (int*)(ws + off);   off += (size_t)(NN + 1) * 4;
    int* cursor   = (int*)(ws + off);   off += (size_t)NN * 4;
    int* part     = (int*)(ws + off);   off += 512;
    short* hbf    = (short*)(ws + off); off += (size_t)NN * EMB * 2;   // 12.8 MB
    int* cnt      = cursor;  // alias: consumed by k_part before k_fix2 rewrites

    hipMemsetAsync(cnt, 0, (size_t)NN * sizeof(int), stream);
    k_proj_hist<<<NPB + NHIST, 256, 0, stream>>>(X, W, Wb, hbf, rcv, cnt);
    k_part<<<NB, 512, 0, stream>>>(cnt, rowptr, part);
    k_fix2<<<NB, 512, 0, stream>>>(part, rowptr, cursor);
    k_edge_attn<<<2048, 256, 0, stream>>>(EF, We, Web, Av, hbf, snd, rcv,
                                          cursor, csr_snd, ex_csr);
    k_agg<<<(NN + 3) / 4, 256, 0, stream>>>(hbf, csr_snd, ex_csr, rowptr, out);
}

// Round 11
// 258.132 us; speedup vs baseline: 2.4608x; 2.4608x over previous
//
#include <hip/hip_runtime.h>
#include <math.h>

#define NN 50000
#define NE 800000
#define IND 256
#define ED 64
#define EMB 128
#define NH 8
#define HD 16

typedef short bf16x8 __attribute__((ext_vector_type(8)));
typedef float f32x4 __attribute__((ext_vector_type(4)));

#define NPT  (NN / 16)                  // 3125 proj tiles
#define NPB  ((NPT + 3) / 4)            // 782 proj blocks
#define NHIST ((NE + 255) / 256)        // 3125 hist blocks
#define NB   ((NN + 511) / 512)         // 98 scan blocks

__device__ __forceinline__ unsigned short rne16(float f) {
    unsigned u = __float_as_uint(f);
    unsigned r = u + 0x7FFFu + ((u >> 16) & 1u);
    return (unsigned short)(r >> 16);
}

__device__ __forceinline__ float bf2f(short s) {
    return __uint_as_float(((unsigned)(unsigned short)s) << 16);
}

__device__ __forceinline__ float mishf(float v) {
    float t = __expf(fminf(v, 20.f));
    float u = 1.f + t;
    u = u * u;
    return v * (u - 1.f) * __builtin_amdgcn_rcpf(u + 1.f);
}

// ------- fused: MFMA node projection + rcv histogram -----------------------
__global__ __launch_bounds__(256) void k_proj_hist(
    const float* __restrict__ X, const float* __restrict__ W,
    const float* __restrict__ b, short* __restrict__ hbf,
    const int* __restrict__ rcv, int* __restrict__ cnt) {
    if (blockIdx.x >= NPB) {            // histogram part
        int e = (blockIdx.x - NPB) * 256 + threadIdx.x;
        if (e < NE) atomicAdd(&cnt[rcv[e]], 1);
        return;
    }
    __shared__ short BHs[IND * EMB];    // 64 KB bf16 fragment tile
    for (int idx = threadIdx.x * 4; idx < IND * EMB; idx += 256 * 4) {
        float4 wv = *(const float4*)&W[idx];
        int k = idx >> 7;
        int col = idx & 127;
        int kk8 = k >> 5, qq = (k & 31) >> 3, j = k & 7;
        float wf[4] = {wv.x, wv.y, wv.z, wv.w};
        #pragma unroll
        for (int i = 0; i < 4; ++i) {
            int cc = (col + i) & 7, lc = (col + i) >> 3;
            int lane = (qq << 4) | lc;
            BHs[(((cc << 3) | kk8) * 64 + lane) * 8 + j] = (short)rne16(wf[i]);
        }
    }
    __syncthreads();

    const int l = threadIdx.x & 63;
    const int lanecol = l & 15;
    const int q = l >> 4;
    const int wid = (blockIdx.x << 2) + (threadIdx.x >> 6);
    const int nW = NPB << 2;

    float4 bv0 = *(const float4*)&b[lanecol * 8];
    float4 bv1 = *(const float4*)&b[lanecol * 8 + 4];
    float wb[8] = {bv0.x, bv0.y, bv0.z, bv0.w, bv1.x, bv1.y, bv1.z, bv1.w};

    for (int tIdx = wid; tIdx < NPT; tIdx += nW) {
        const int n0 = tIdx * 16;
        f32x4 acc[8];
        #pragma unroll
        for (int c = 0; c < 8; ++c) acc[c] = (f32x4){0.f, 0.f, 0.f, 0.f};
        #pragma unroll
        for (int kk8 = 0; kk8 < 8; ++kk8) {
            const float* ar = X + (size_t)(n0 + lanecol) * IND + kk8 * 32 + q * 8;
            float4 a0 = *(const float4*)ar;
            float4 a1 = *(const float4*)(ar + 4);
            float faf[8] = {a0.x, a0.y, a0.z, a0.w, a1.x, a1.y, a1.z, a1.w};
            bf16x8 ahi;
            #pragma unroll
            for (int j = 0; j < 8; ++j) ahi[j] = (short)rne16(faf[j]);
            #pragma unroll
            for (int c = 0; c < 8; ++c) {
                bf16x8 bh = *(bf16x8*)&BHs[(((c << 3) | kk8) * 64 + l) * 8];
                acc[c] = __builtin_amdgcn_mfma_f32_16x16x32_bf16(ahi, bh, acc[c], 0, 0, 0);
            }
        }
        #pragma unroll
        for (int r = 0; r < 4; ++r) {
            const int node = n0 + (q << 2) + r;
            bf16x8 ov;
            #pragma unroll
            for (int c = 0; c < 8; ++c) ov[c] = (short)rne16(acc[c][r] + wb[c]);
            *(bf16x8*)(hbf + (size_t)node * EMB + lanecol * 8) = ov;
        }
    }
}

// ---------------- CSR build: per-block scan, merged fixup ------------------
__global__ __launch_bounds__(512) void k_part(const int* __restrict__ cnt,
                                              int* __restrict__ rowptr,
                                              int* __restrict__ part) {
    __shared__ int sm[512];
    const int t = threadIdx.x;
    const int idx = blockIdx.x * 512 + t;
    int v = (idx < NN) ? cnt[idx] : 0;
    sm[t] = v;
    __syncthreads();
    #pragma unroll
    for (int off = 1; off < 512; off <<= 1) {
        int y = (t >= off) ? sm[t - off] : 0;
        __syncthreads();
        sm[t] += y;
        __syncthreads();
    }
    if (idx < NN) rowptr[idx] = sm[t] - v;
    if (t == 511) part[blockIdx.x] = sm[511];
}

__global__ __launch_bounds__(512) void k_fix2(const int* __restrict__ part,
                                              int* __restrict__ rowptr,
                                              int* __restrict__ cursor) {
    __shared__ int sm[128];
    const int t = threadIdx.x;
    if (t < 128) sm[t] = (t < NB) ? part[t] : 0;
    __syncthreads();
    #pragma unroll
    for (int off = 1; off < 128; off <<= 1) {
        int y = 0;
        if (t < 128 && t >= off) y = sm[t - off];
        __syncthreads();
        if (t < 128) sm[t] += y;
        __syncthreads();
    }
    const int boff = (blockIdx.x > 0) ? sm[blockIdx.x - 1] : 0;
    const int idx = blockIdx.x * 512 + t;
    if (idx < NN) {
        int r = rowptr[idx] + boff;
        rowptr[idx] = r;
        cursor[idx] = r;
    }
    if (blockIdx.x == 0 && t == 0) rowptr[NN] = NE;
}

// ---------- fused edge pass: early gathers + parallel atomics --------------
__global__ __launch_bounds__(256) void k_edge_attn(
    const float* __restrict__ EF, const float* __restrict__ We,
    const float* __restrict__ Web, const float* __restrict__ Av,
    const short* __restrict__ hbf, const int* __restrict__ snd,
    const int* __restrict__ rcv, int* __restrict__ cursor,
    int* __restrict__ csr_snd, float* __restrict__ ex_csr) {
    __shared__ short BHs[ED * EMB];     // 16 KB bf16 fragment tile
    __shared__ float2 WA[144];          // (Web, Av) pairs, stride-9 padded
    for (int idx = threadIdx.x * 4; idx < ED * EMB; idx += 256 * 4) {
        float4 wv = *(const float4*)&We[idx];
        int k = idx >> 7;
        int col = idx & 127;
        int kk = k >> 5, qq = (k & 31) >> 3, j = k & 7;
        float wf[4] = {wv.x, wv.y, wv.z, wv.w};
        #pragma unroll
        for (int i = 0; i < 4; ++i) {
            int cc = (col + i) & 7, lc = (col + i) >> 3;
            int lane = (qq << 4) | lc;
            BHs[(((cc << 1) | kk) * 64 + lane) * 8 + j] = (short)rne16(wf[i]);
        }
    }
    if (threadIdx.x < 128) {
        int c = threadIdx.x & 7, lc = threadIdx.x >> 3;
        WA[lc * 9 + c] = make_float2(Web[threadIdx.x], Av[threadIdx.x]);
    }
    __syncthreads();

    const int l = threadIdx.x & 63;
    const int lanecol = l & 15;
    const int q = l >> 4;
    const int gbase = l & 48;           // group base lane (q*16)
    const int wid = (blockIdx.x << 2) + (threadIdx.x >> 6);
    const int nW = gridDim.x << 2;
    const int NT = NE / 16;

    for (int tIdx = wid; tIdx < NT; tIdx += nW) {
        const int e0 = tIdx * 16;
        const int eb = e0 + (q << 2);   // this group's 4 edges

        // --- group-uniform sender/receiver quads (16B loads) ---
        int4 s4 = *(const int4*)&snd[eb];
        int4 r4 = *(const int4*)&rcv[eb];
        int sA[4] = {s4.x, s4.y, s4.z, s4.w};
        int rA[4] = {r4.x, r4.y, r4.z, r4.w};

        // --- issue ALL 8 h-row gathers early (hidden under MFMA) ---
        bf16x8 hsv[4], hrv[4];
        #pragma unroll
        for (int r = 0; r < 4; ++r) {
            hsv[r] = *(const bf16x8*)(hbf + (size_t)sA[r] * EMB + lanecol * 8);
            hrv[r] = *(const bf16x8*)(hbf + (size_t)rA[r] * EMB + lanecol * 8);
        }

        // --- parallel bucket atomics: lanes lanecol<4 own r=lanecol ---
        int pos4 = 0;
        if (lanecol < 4) {
            pos4 = atomicAdd(&cursor[rA[lanecol]], 1);
            csr_snd[pos4] = sA[lanecol];
        }

        // --- MFMA: kk-outer so ahi0 dies before ahi1 is built ---
        f32x4 acc[8];
        #pragma unroll
        for (int c = 0; c < 8; ++c) acc[c] = (f32x4){0.f, 0.f, 0.f, 0.f};
        const float* ar = EF + (size_t)(e0 + lanecol) * ED + q * 8;
        #pragma unroll
        for (int kk = 0; kk < 2; ++kk) {
            float4 a0 = *(const float4*)(ar + kk * 32);
            float4 a1 = *(const float4*)(ar + kk * 32 + 4);
            bf16x8 ahi;
            ahi[0] = (short)rne16(a0.x); ahi[1] = (short)rne16(a0.y);
            ahi[2] = (short)rne16(a0.z); ahi[3] = (short)rne16(a0.w);
            ahi[4] = (short)rne16(a1.x); ahi[5] = (short)rne16(a1.y);
            ahi[6] = (short)rne16(a1.z); ahi[7] = (short)rne16(a1.w);
            #pragma unroll
            for (int c = 0; c < 8; ++c) {
                bf16x8 bh = *(bf16x8*)&BHs[(((c << 1) | kk) * 64 + l) * 8];
                acc[c] = __builtin_amdgcn_mfma_f32_16x16x32_bf16(ahi, bh, acc[c], 0, 0, 0);
            }
        }

        // --- epilogue: consume prefetched rows, broadcast pos per r ---
        #pragma unroll
        for (int r = 0; r < 4; ++r) {
            float pp = 0.f;
            #pragma unroll
            for (int c = 0; c < 8; ++c) {
                float2 wa = WA[lanecol * 9 + c];
                float v = acc[c][r] + wa.x + bf2f(hsv[r][c]) + bf2f(hrv[r][c]);
                pp = fmaf(mishf(v), wa.y, pp);
            }
            pp += __shfl_xor(pp, 1, 16);
            const int pos = __shfl(pos4, gbase + r, 64);
            if ((lanecol & 1) == 0)
                ex_csr[(size_t)pos * NH + (lanecol >> 1)] = __expf(pp);
        }
    }
}

// --------- segmented aggregation: bf16 h, lane owns cols 2l,2l+1 -----------
__global__ __launch_bounds__(256) void k_agg(
    const short* __restrict__ hbf, const int* __restrict__ csr_snd,
    const float* __restrict__ ex_csr, const int* __restrict__ rowptr,
    float* __restrict__ out) {
    const int l = threadIdx.x & 63;
    const int node = blockIdx.x * 4 + (threadIdx.x >> 6);
    if (node >= NN) return;
    const int beg = rowptr[node], end = rowptr[node + 1];
    const int h = l >> 3;
    float a0 = 0.f, a1 = 0.f, den = 0.f;
    int j = beg;
    for (; j + 4 <= end; j += 4) {
        int s[4];
        float ex[4];
        unsigned hv[4];
        #pragma unroll
        for (int i = 0; i < 4; ++i) s[i] = csr_snd[j + i];
        #pragma unroll
        for (int i = 0; i < 4; ++i) ex[i] = ex_csr[(size_t)(j + i) * NH + h];
        #pragma unroll
        for (int i = 0; i < 4; ++i)
            hv[i] = *(const unsigned*)(hbf + (size_t)s[i] * EMB + 2 * l);
        #pragma unroll
        for (int i = 0; i < 4; ++i) {
            a0 = fmaf(ex[i], bf2f((short)(hv[i] & 0xFFFF)), a0);
            a1 = fmaf(ex[i], bf2f((short)(hv[i] >> 16)), a1);
            den += ex[i];
        }
    }
    for (; j < end; ++j) {
        float ex = ex_csr[(size_t)j * NH + h];
        unsigned hv = *(const unsigned*)(hbf + (size_t)csr_snd[j] * EMB + 2 * l);
        a0 = fmaf(ex, bf2f((short)(hv & 0xFFFF)), a0);
        a1 = fmaf(ex, bf2f((short)(hv >> 16)), a1);
        den += ex;
    }
    float rd = (end > beg) ? __builtin_amdgcn_rcpf(den) : 0.f;
    float2 o;
    o.x = a0 * rd;
    o.y = a1 * rd;
    *(float2*)&out[(size_t)node * EMB + 2 * l] = o;
}

extern "C" void kernel_launch(void* const* d_in, const int* in_sizes, int n_in,
                              void* d_out, int out_size, void* d_ws, size_t ws_size,
                              hipStream_t stream) {
    const float* X   = (const float*)d_in[0];
    const float* EF  = (const float*)d_in[1];
    const float* W   = (const float*)d_in[2];
    const float* Wb  = (const float*)d_in[3];
    const float* We  = (const float*)d_in[4];
    const float* Web = (const float*)d_in[5];
    const float* Av  = (const float*)d_in[6];
    const int* snd   = (const int*)d_in[7];
    const int* rcv   = (const int*)d_in[8];
    float* out = (float*)d_out;

    char* ws = (char*)d_ws;
    size_t off = 0;
    float* ex_csr = (float*)(ws + off); off += (size_t)NE * NH * 4;    // 25.6 MB
    int* csr_snd  = (int*)(ws + off);   off += (size_t)NE * 4;         // 3.2 MB
    int* rowptr   = (int*)(ws + off);   off += (size_t)(NN + 1) * 4;
    int* cursor   = (int*)(ws + off);   off += (size_t)NN * 4;
    int* part     = (int*)(ws + off);   off += 512;
    short* hbf    = (short*)(ws + off); off += (size_t)NN * EMB * 2;   // 12.8 MB
    int* cnt      = cursor;  // alias: consumed by k_part before k_fix2 rewrites

    hipMemsetAsync(cnt, 0, (size_t)NN * sizeof(int), stream);
    k_proj_hist<<<NPB + NHIST, 256, 0, stream>>>(X, W, Wb, hbf, rcv, cnt);
    k_part<<<NB, 512, 0, stream>>>(cnt, rowptr, part);
    k_fix2<<<NB, 512, 0, stream>>>(part, rowptr, cursor);
    k_edge_attn<<<2048, 256, 0, stream>>>(EF, We, Web, Av, hbf, snd, rcv,
                                          cursor, csr_snd, ex_csr);
    k_agg<<<(NN + 3) / 4, 256, 0, stream>>>(hbf, csr_snd, ex_csr, rowptr, out);
}

// Round 12
// 252.000 us; speedup vs baseline: 2.5207x; 1.0243x over previous
//
#include <hip/hip_runtime.h>
#include <math.h>

#define NN 50000
#define NE 800000
#define IND 256
#define ED 64
#define EMB 128
#define NH 8
#define HD 16

typedef short bf16x8 __attribute__((ext_vector_type(8)));
typedef float f32x4 __attribute__((ext_vector_type(4)));

#define NPT  (NN / 16)                  // 3125 proj tiles
#define NPB  ((NPT + 3) / 4)            // 782 proj blocks
#define NHIST ((NE + 255) / 256)        // 3125 hist blocks
#define NB   ((NN + 511) / 512)         // 98 scan blocks

__device__ __forceinline__ unsigned short rne16(float f) {
    unsigned u = __float_as_uint(f);
    unsigned r = u + 0x7FFFu + ((u >> 16) & 1u);
    return (unsigned short)(r >> 16);
}

__device__ __forceinline__ float bf2f(short s) {
    return __uint_as_float(((unsigned)(unsigned short)s) << 16);
}

__device__ __forceinline__ float mishf(float v) {
    float t = __expf(fminf(v, 20.f));
    float u = 1.f + t;
    u = u * u;
    return v * (u - 1.f) * __builtin_amdgcn_rcpf(u + 1.f);
}

// ------- fused: MFMA node projection + rcv histogram -----------------------
__global__ __launch_bounds__(256) void k_proj_hist(
    const float* __restrict__ X, const float* __restrict__ W,
    const float* __restrict__ b, short* __restrict__ hbf,
    const int* __restrict__ rcv, int* __restrict__ cnt) {
    if (blockIdx.x >= NPB) {            // histogram part
        int e = (blockIdx.x - NPB) * 256 + threadIdx.x;
        if (e < NE) atomicAdd(&cnt[rcv[e]], 1);
        return;
    }
    __shared__ short BHs[IND * EMB];    // 64 KB bf16 fragment tile
    for (int idx = threadIdx.x * 4; idx < IND * EMB; idx += 256 * 4) {
        float4 wv = *(const float4*)&W[idx];
        int k = idx >> 7;
        int col = idx & 127;
        int kk8 = k >> 5, qq = (k & 31) >> 3, j = k & 7;
        float wf[4] = {wv.x, wv.y, wv.z, wv.w};
        #pragma unroll
        for (int i = 0; i < 4; ++i) {
            int cc = (col + i) & 7, lc = (col + i) >> 3;
            int lane = (qq << 4) | lc;
            BHs[(((cc << 3) | kk8) * 64 + lane) * 8 + j] = (short)rne16(wf[i]);
        }
    }
    __syncthreads();

    const int l = threadIdx.x & 63;
    const int lanecol = l & 15;
    const int q = l >> 4;
    const int wid = (blockIdx.x << 2) + (threadIdx.x >> 6);
    const int nW = NPB << 2;

    float4 bv0 = *(const float4*)&b[lanecol * 8];
    float4 bv1 = *(const float4*)&b[lanecol * 8 + 4];
    float wb[8] = {bv0.x, bv0.y, bv0.z, bv0.w, bv1.x, bv1.y, bv1.z, bv1.w};

    for (int tIdx = wid; tIdx < NPT; tIdx += nW) {
        const int n0 = tIdx * 16;
        f32x4 acc[8];
        #pragma unroll
        for (int c = 0; c < 8; ++c) acc[c] = (f32x4){0.f, 0.f, 0.f, 0.f};
        #pragma unroll
        for (int kk8 = 0; kk8 < 8; ++kk8) {
            const float* ar = X + (size_t)(n0 + lanecol) * IND + kk8 * 32 + q * 8;
            float4 a0 = *(const float4*)ar;
            float4 a1 = *(const float4*)(ar + 4);
            float faf[8] = {a0.x, a0.y, a0.z, a0.w, a1.x, a1.y, a1.z, a1.w};
            bf16x8 ahi;
            #pragma unroll
            for (int j = 0; j < 8; ++j) ahi[j] = (short)rne16(faf[j]);
            #pragma unroll
            for (int c = 0; c < 8; ++c) {
                bf16x8 bh = *(bf16x8*)&BHs[(((c << 3) | kk8) * 64 + l) * 8];
                acc[c] = __builtin_amdgcn_mfma_f32_16x16x32_bf16(ahi, bh, acc[c], 0, 0, 0);
            }
        }
        #pragma unroll
        for (int r = 0; r < 4; ++r) {
            const int node = n0 + (q << 2) + r;
            bf16x8 ov;
            #pragma unroll
            for (int c = 0; c < 8; ++c) ov[c] = (short)rne16(acc[c][r] + wb[c]);
            *(bf16x8*)(hbf + (size_t)node * EMB + lanecol * 8) = ov;
        }
    }
}

// ---------------- CSR build: per-block scan, merged fixup ------------------
__global__ __launch_bounds__(512) void k_part(const int* __restrict__ cnt,
                                              int* __restrict__ rowptr,
                                              int* __restrict__ part) {
    __shared__ int sm[512];
    const int t = threadIdx.x;
    const int idx = blockIdx.x * 512 + t;
    int v = (idx < NN) ? cnt[idx] : 0;
    sm[t] = v;
    __syncthreads();
    #pragma unroll
    for (int off = 1; off < 512; off <<= 1) {
        int y = (t >= off) ? sm[t - off] : 0;
        __syncthreads();
        sm[t] += y;
        __syncthreads();
    }
    if (idx < NN) rowptr[idx] = sm[t] - v;
    if (t == 511) part[blockIdx.x] = sm[511];
}

__global__ __launch_bounds__(512) void k_fix2(const int* __restrict__ part,
                                              int* __restrict__ rowptr,
                                              int* __restrict__ cursor) {
    __shared__ int sm[128];
    const int t = threadIdx.x;
    if (t < 128) sm[t] = (t < NB) ? part[t] : 0;
    __syncthreads();
    #pragma unroll
    for (int off = 1; off < 128; off <<= 1) {
        int y = 0;
        if (t < 128 && t >= off) y = sm[t - off];
        __syncthreads();
        if (t < 128) sm[t] += y;
        __syncthreads();
    }
    const int boff = (blockIdx.x > 0) ? sm[blockIdx.x - 1] : 0;
    const int idx = blockIdx.x * 512 + t;
    if (idx < NN) {
        int r = rowptr[idx] + boff;
        rowptr[idx] = r;
        cursor[idx] = r;
    }
    if (blockIdx.x == 0 && t == 0) rowptr[NN] = NE;
}

// ---------- fused edge pass: 1-tile software pipeline ----------------------
// Per tile t: snd/rcv + EF(bf16) were prefetched during t-1, so gathers and
// the bucket atomic issue immediately; EF/snd/rcv for t+1 load under t's
// MFMA+epilogue. Raw EF floats are transient (converted after epilogue).
__global__ __launch_bounds__(256) void k_edge_attn(
    const float* __restrict__ EF, const float* __restrict__ We,
    const float* __restrict__ Web, const float* __restrict__ Av,
    const short* __restrict__ hbf, const int* __restrict__ snd,
    const int* __restrict__ rcv, int* __restrict__ cursor,
    int* __restrict__ csr_snd, float* __restrict__ ex_csr) {
    __shared__ short BHs[ED * EMB];     // 16 KB bf16 fragment tile
    __shared__ float2 WA[144];          // (Web, Av) pairs, stride-9 padded
    for (int idx = threadIdx.x * 4; idx < ED * EMB; idx += 256 * 4) {
        float4 wv = *(const float4*)&We[idx];
        int k = idx >> 7;
        int col = idx & 127;
        int kk = k >> 5, qq = (k & 31) >> 3, j = k & 7;
        float wf[4] = {wv.x, wv.y, wv.z, wv.w};
        #pragma unroll
        for (int i = 0; i < 4; ++i) {
            int cc = (col + i) & 7, lc = (col + i) >> 3;
            int lane = (qq << 4) | lc;
            BHs[(((cc << 1) | kk) * 64 + lane) * 8 + j] = (short)rne16(wf[i]);
        }
    }
    if (threadIdx.x < 128) {
        int c = threadIdx.x & 7, lc = threadIdx.x >> 3;
        WA[lc * 9 + c] = make_float2(Web[threadIdx.x], Av[threadIdx.x]);
    }
    __syncthreads();

    const int l = threadIdx.x & 63;
    const int lanecol = l & 15;
    const int q = l >> 4;
    const int gbase = l & 48;
    const int wid = (blockIdx.x << 2) + (threadIdx.x >> 6);
    const int nW = gridDim.x << 2;
    const int NT = NE / 16;

    int tIdx = wid;
    if (tIdx >= NT) return;

    // ---- prologue: load tile-0 snd/rcv and EF, convert EF to bf16 ----
    int4 s4, r4;
    bf16x8 ahi0, ahi1;
    {
        const int eb = tIdx * 16 + (q << 2);
        s4 = *(const int4*)&snd[eb];
        r4 = *(const int4*)&rcv[eb];
        const float* ar = EF + (size_t)(tIdx * 16 + lanecol) * ED + q * 8;
        float4 a0 = *(const float4*)ar;
        float4 a1 = *(const float4*)(ar + 4);
        float4 a2 = *(const float4*)(ar + 32);
        float4 a3 = *(const float4*)(ar + 36);
        ahi0[0] = (short)rne16(a0.x); ahi0[1] = (short)rne16(a0.y);
        ahi0[2] = (short)rne16(a0.z); ahi0[3] = (short)rne16(a0.w);
        ahi0[4] = (short)rne16(a1.x); ahi0[5] = (short)rne16(a1.y);
        ahi0[6] = (short)rne16(a1.z); ahi0[7] = (short)rne16(a1.w);
        ahi1[0] = (short)rne16(a2.x); ahi1[1] = (short)rne16(a2.y);
        ahi1[2] = (short)rne16(a2.z); ahi1[3] = (short)rne16(a2.w);
        ahi1[4] = (short)rne16(a3.x); ahi1[5] = (short)rne16(a3.y);
        ahi1[6] = (short)rne16(a3.z); ahi1[7] = (short)rne16(a3.w);
    }

    while (true) {
        const int tn = tIdx + nW;
        const bool more = (tn < NT);

        // ---- gathers for current tile: operands already resident ----
        bf16x8 hsvA = *(const bf16x8*)(hbf + (size_t)s4.x * EMB + lanecol * 8);
        bf16x8 hrvA = *(const bf16x8*)(hbf + (size_t)r4.x * EMB + lanecol * 8);
        bf16x8 hsvB = *(const bf16x8*)(hbf + (size_t)s4.y * EMB + lanecol * 8);
        bf16x8 hrvB = *(const bf16x8*)(hbf + (size_t)r4.y * EMB + lanecol * 8);
        bf16x8 hsvC = *(const bf16x8*)(hbf + (size_t)s4.z * EMB + lanecol * 8);
        bf16x8 hrvC = *(const bf16x8*)(hbf + (size_t)r4.z * EMB + lanecol * 8);
        bf16x8 hsvD = *(const bf16x8*)(hbf + (size_t)s4.w * EMB + lanecol * 8);
        bf16x8 hrvD = *(const bf16x8*)(hbf + (size_t)r4.w * EMB + lanecol * 8);

        // ---- bucket atomic (lanes 0-3 of each group own one edge) ----
        int ssel = (lanecol == 0) ? s4.x : (lanecol == 1) ? s4.y
                 : (lanecol == 2) ? s4.z : s4.w;
        int rsel = (lanecol == 0) ? r4.x : (lanecol == 1) ? r4.y
                 : (lanecol == 2) ? r4.z : r4.w;
        int pos4 = 0;
        if (lanecol < 4) {
            pos4 = atomicAdd(&cursor[rsel], 1);
            csr_snd[pos4] = ssel;
        }

        // ---- prefetch next tile's snd/rcv + raw EF ----
        int4 s4n, r4n;
        float4 f0, f1, f2, f3;
        if (more) {
            const int ebn = tn * 16 + (q << 2);
            s4n = *(const int4*)&snd[ebn];
            r4n = *(const int4*)&rcv[ebn];
            const float* arn = EF + (size_t)(tn * 16 + lanecol) * ED + q * 8;
            f0 = *(const float4*)arn;
            f1 = *(const float4*)(arn + 4);
            f2 = *(const float4*)(arn + 32);
            f3 = *(const float4*)(arn + 36);
        }

        // ---- MFMA on pre-converted fragments ----
        f32x4 acc[8];
        #pragma unroll
        for (int c = 0; c < 8; ++c) acc[c] = (f32x4){0.f, 0.f, 0.f, 0.f};
        #pragma unroll
        for (int c = 0; c < 8; ++c) {
            bf16x8 b0 = *(bf16x8*)&BHs[(((c << 1) | 0) * 64 + l) * 8];
            acc[c] = __builtin_amdgcn_mfma_f32_16x16x32_bf16(ahi0, b0, acc[c], 0, 0, 0);
            bf16x8 b1 = *(bf16x8*)&BHs[(((c << 1) | 1) * 64 + l) * 8];
            acc[c] = __builtin_amdgcn_mfma_f32_16x16x32_bf16(ahi1, b1, acc[c], 0, 0, 0);
        }

        // ---- epilogue ----
        #pragma unroll
        for (int r = 0; r < 4; ++r) {
            const bf16x8& hs = (r == 0) ? hsvA : (r == 1) ? hsvB : (r == 2) ? hsvC : hsvD;
            const bf16x8& hr = (r == 0) ? hrvA : (r == 1) ? hrvB : (r == 2) ? hrvC : hrvD;
            float pp = 0.f;
            #pragma unroll
            for (int c = 0; c < 8; ++c) {
                float2 wa = WA[lanecol * 9 + c];
                float v = acc[c][r] + wa.x + bf2f(hs[c]) + bf2f(hr[c]);
                pp = fmaf(mishf(v), wa.y, pp);
            }
            pp += __shfl_xor(pp, 1, 16);
            const int pos = __shfl(pos4, gbase + r, 64);
            if ((lanecol & 1) == 0)
                ex_csr[(size_t)pos * NH + (lanecol >> 1)] = __expf(pp);
        }

        if (!more) break;
        // ---- rotate: convert prefetched EF (raw floats die here) ----
        ahi0[0] = (short)rne16(f0.x); ahi0[1] = (short)rne16(f0.y);
        ahi0[2] = (short)rne16(f0.z); ahi0[3] = (short)rne16(f0.w);
        ahi0[4] = (short)rne16(f1.x); ahi0[5] = (short)rne16(f1.y);
        ahi0[6] = (short)rne16(f1.z); ahi0[7] = (short)rne16(f1.w);
        ahi1[0] = (short)rne16(f2.x); ahi1[1] = (short)rne16(f2.y);
        ahi1[2] = (short)rne16(f2.z); ahi1[3] = (short)rne16(f2.w);
        ahi1[4] = (short)rne16(f3.x); ahi1[5] = (short)rne16(f3.y);
        ahi1[6] = (short)rne16(f3.z); ahi1[7] = (short)rne16(f3.w);
        s4 = s4n;
        r4 = r4n;
        tIdx = tn;
    }
}

// --------- segmented aggregation: bf16 h, lane owns cols 2l,2l+1 -----------
__global__ __launch_bounds__(256) void k_agg(
    const short* __restrict__ hbf, const int* __restrict__ csr_snd,
    const float* __restrict__ ex_csr, const int* __restrict__ rowptr,
    float* __restrict__ out) {
    const int l = threadIdx.x & 63;
    const int node = blockIdx.x * 4 + (threadIdx.x >> 6);
    if (node >= NN) return;
    const int beg = rowptr[node], end = rowptr[node + 1];
    const int h = l >> 3;
    float a0 = 0.f, a1 = 0.f, den = 0.f;
    int j = beg;
    for (; j + 4 <= end; j += 4) {
        int s[4];
        float ex[4];
        unsigned hv[4];
        #pragma unroll
        for (int i = 0; i < 4; ++i) s[i] = csr_snd[j + i];
        #pragma unroll
        for (int i = 0; i < 4; ++i) ex[i] = ex_csr[(size_t)(j + i) * NH + h];
        #pragma unroll
        for (int i = 0; i < 4; ++i)
            hv[i] = *(const unsigned*)(hbf + (size_t)s[i] * EMB + 2 * l);
        #pragma unroll
        for (int i = 0; i < 4; ++i) {
            a0 = fmaf(ex[i], bf2f((short)(hv[i] & 0xFFFF)), a0);
            a1 = fmaf(ex[i], bf2f((short)(hv[i] >> 16)), a1);
            den += ex[i];
        }
    }
    for (; j < end; ++j) {
        float ex = ex_csr[(size_t)j * NH + h];
        unsigned hv = *(const unsigned*)(hbf + (size_t)csr_snd[j] * EMB + 2 * l);
        a0 = fmaf(ex, bf2f((short)(hv & 0xFFFF)), a0);
        a1 = fmaf(ex, bf2f((short)(hv >> 16)), a1);
        den += ex;
    }
    float rd = (end > beg) ? __builtin_amdgcn_rcpf(den) : 0.f;
    float2 o;
    o.x = a0 * rd;
    o.y = a1 * rd;
    *(float2*)&out[(size_t)node * EMB + 2 * l] = o;
}

extern "C" void kernel_launch(void* const* d_in, const int* in_sizes, int n_in,
                              void* d_out, int out_size, void* d_ws, size_t ws_size,
                              hipStream_t stream) {
    const float* X   = (const float*)d_in[0];
    const float* EF  = (const float*)d_in[1];
    const float* W   = (const float*)d_in[2];
    const float* Wb  = (const float*)d_in[3];
    const float* We  = (const float*)d_in[4];
    const float* Web = (const float*)d_in[5];
    const float* Av  = (const float*)d_in[6];
    const int* snd   = (const int*)d_in[7];
    const int* rcv   = (const int*)d_in[8];
    float* out = (float*)d_out;

    char* ws = (char*)d_ws;
    size_t off = 0;
    float* ex_csr = (float*)(ws + off); off += (size_t)NE * NH * 4;    // 25.6 MB
    int* csr_snd  = (int*)(ws + off);   off += (size_t)NE * 4;         // 3.2 MB
    int* rowptr   = (int*)(ws + off);   off += (size_t)(NN + 1) * 4;
    int* cursor   = (int*)(ws + off);   off += (size_t)NN * 4;
    int* part     = (int*)(ws + off);   off += 512;
    short* hbf    = (short*)(ws + off); off += (size_t)NN * EMB * 2;   // 12.8 MB
    int* cnt      = cursor;  // alias: consumed by k_part before k_fix2 rewrites

    hipMemsetAsync(cnt, 0, (size_t)NN * sizeof(int), stream);
    k_proj_hist<<<NPB + NHIST, 256, 0, stream>>>(X, W, Wb, hbf, rcv, cnt);
    k_part<<<NB, 512, 0, stream>>>(cnt, rowptr, part);
    k_fix2<<<NB, 512, 0, stream>>>(part, rowptr, cursor);
    k_edge_attn<<<2048, 256, 0, stream>>>(EF, We, Web, Av, hbf, snd, rcv,
                                          cursor, csr_snd, ex_csr);
    k_agg<<<(NN + 3) / 4, 256, 0, stream>>>(hbf, csr_snd, ex_csr, rowptr, out);
}

// Round 13
// 250.726 us; speedup vs baseline: 2.5335x; 1.0051x over previous
//
#include <hip/hip_runtime.h>
#include <math.h>

#define NN 50000
#define NE 800000
#define IND 256
#define ED 64
#define EMB 128
#define NH 8
#define HD 16

typedef short bf16x8 __attribute__((ext_vector_type(8)));
typedef float f32x4 __attribute__((ext_vector_type(4)));

#define NPT  (NN / 16)                  // 3125 proj tiles
#define NPB  ((NPT + 3) / 4)            // 782 proj blocks
#define NHIST ((NE + 255) / 256)        // 3125 hist blocks
#define NB   ((NN + 511) / 512)         // 98 scan blocks

__device__ __forceinline__ unsigned short rne16(float f) {
    unsigned u = __float_as_uint(f);
    unsigned r = u + 0x7FFFu + ((u >> 16) & 1u);
    return (unsigned short)(r >> 16);
}

__device__ __forceinline__ float bf2f(short s) {
    return __uint_as_float(((unsigned)(unsigned short)s) << 16);
}

__device__ __forceinline__ float mishf(float v) {
    float t = __expf(fminf(v, 20.f));
    float u = 1.f + t;
    u = u * u;
    return v * (u - 1.f) * __builtin_amdgcn_rcpf(u + 1.f);
}

// ------- fused: MFMA node projection + rcv histogram -----------------------
__global__ __launch_bounds__(256) void k_proj_hist(
    const float* __restrict__ X, const float* __restrict__ W,
    const float* __restrict__ b, short* __restrict__ hbf,
    const int* __restrict__ rcv, int* __restrict__ cnt) {
    if (blockIdx.x >= NPB) {            // histogram part
        int e = (blockIdx.x - NPB) * 256 + threadIdx.x;
        if (e < NE) atomicAdd(&cnt[rcv[e]], 1);
        return;
    }
    __shared__ short BHs[IND * EMB];    // 64 KB bf16 fragment tile
    for (int idx = threadIdx.x * 4; idx < IND * EMB; idx += 256 * 4) {
        float4 wv = *(const float4*)&W[idx];
        int k = idx >> 7;
        int col = idx & 127;
        int kk8 = k >> 5, qq = (k & 31) >> 3, j = k & 7;
        float wf[4] = {wv.x, wv.y, wv.z, wv.w};
        #pragma unroll
        for (int i = 0; i < 4; ++i) {
            int cc = (col + i) & 7, lc = (col + i) >> 3;
            int lane = (qq << 4) | lc;
            BHs[(((cc << 3) | kk8) * 64 + lane) * 8 + j] = (short)rne16(wf[i]);
        }
    }
    __syncthreads();

    const int l = threadIdx.x & 63;
    const int lanecol = l & 15;
    const int q = l >> 4;
    const int wid = (blockIdx.x << 2) + (threadIdx.x >> 6);
    const int nW = NPB << 2;

    float4 bv0 = *(const float4*)&b[lanecol * 8];
    float4 bv1 = *(const float4*)&b[lanecol * 8 + 4];
    float wb[8] = {bv0.x, bv0.y, bv0.z, bv0.w, bv1.x, bv1.y, bv1.z, bv1.w};

    for (int tIdx = wid; tIdx < NPT; tIdx += nW) {
        const int n0 = tIdx * 16;
        f32x4 acc[8];
        #pragma unroll
        for (int c = 0; c < 8; ++c) acc[c] = (f32x4){0.f, 0.f, 0.f, 0.f};
        #pragma unroll
        for (int kk8 = 0; kk8 < 8; ++kk8) {
            const float* ar = X + (size_t)(n0 + lanecol) * IND + kk8 * 32 + q * 8;
            float4 a0 = *(const float4*)ar;
            float4 a1 = *(const float4*)(ar + 4);
            float faf[8] = {a0.x, a0.y, a0.z, a0.w, a1.x, a1.y, a1.z, a1.w};
            bf16x8 ahi;
            #pragma unroll
            for (int j = 0; j < 8; ++j) ahi[j] = (short)rne16(faf[j]);
            #pragma unroll
            for (int c = 0; c < 8; ++c) {
                bf16x8 bh = *(bf16x8*)&BHs[(((c << 3) | kk8) * 64 + l) * 8];
                acc[c] = __builtin_amdgcn_mfma_f32_16x16x32_bf16(ahi, bh, acc[c], 0, 0, 0);
            }
        }
        #pragma unroll
        for (int r = 0; r < 4; ++r) {
            const int node = n0 + (q << 2) + r;
            bf16x8 ov;
            #pragma unroll
            for (int c = 0; c < 8; ++c) ov[c] = (short)rne16(acc[c][r] + wb[c]);
            *(bf16x8*)(hbf + (size_t)node * EMB + lanecol * 8) = ov;
        }
    }
}

// ---------------- CSR build: per-block scan, merged fixup ------------------
__global__ __launch_bounds__(512) void k_part(const int* __restrict__ cnt,
                                              int* __restrict__ rowptr,
                                              int* __restrict__ part) {
    __shared__ int sm[512];
    const int t = threadIdx.x;
    const int idx = blockIdx.x * 512 + t;
    int v = (idx < NN) ? cnt[idx] : 0;
    sm[t] = v;
    __syncthreads();
    #pragma unroll
    for (int off = 1; off < 512; off <<= 1) {
        int y = (t >= off) ? sm[t - off] : 0;
        __syncthreads();
        sm[t] += y;
        __syncthreads();
    }
    if (idx < NN) rowptr[idx] = sm[t] - v;
    if (t == 511) part[blockIdx.x] = sm[511];
}

__global__ __launch_bounds__(512) void k_fix2(const int* __restrict__ part,
                                              int* __restrict__ rowptr,
                                              int* __restrict__ cursor) {
    __shared__ int sm[128];
    const int t = threadIdx.x;
    if (t < 128) sm[t] = (t < NB) ? part[t] : 0;
    __syncthreads();
    #pragma unroll
    for (int off = 1; off < 128; off <<= 1) {
        int y = 0;
        if (t < 128 && t >= off) y = sm[t - off];
        __syncthreads();
        if (t < 128) sm[t] += y;
        __syncthreads();
    }
    const int boff = (blockIdx.x > 0) ? sm[blockIdx.x - 1] : 0;
    const int idx = blockIdx.x * 512 + t;
    if (idx < NN) {
        int r = rowptr[idx] + boff;
        rowptr[idx] = r;
        cursor[idx] = r;
    }
    if (blockIdx.x == 0 && t == 0) rowptr[NN] = NE;
}

// ---------- fused edge pass: interleaved MFMA+epilogue (VGPR-lean) ---------
// acc liveness cut 32->4: chunk c's MFMA result is consumed immediately by
// its slice of the mish/logit epilogue; only pp[4] accumulates across chunks.
__global__ __launch_bounds__(256) void k_edge_attn(
    const float* __restrict__ EF, const float* __restrict__ We,
    const float* __restrict__ Web, const float* __restrict__ Av,
    const short* __restrict__ hbf, const int* __restrict__ snd,
    const int* __restrict__ rcv, int* __restrict__ cursor,
    int* __restrict__ csr_snd, float* __restrict__ ex_csr) {
    __shared__ short BHs[ED * EMB];     // 16 KB bf16 fragment tile
    __shared__ float2 WA[144];          // (Web, Av) pairs, stride-9 padded
    for (int idx = threadIdx.x * 4; idx < ED * EMB; idx += 256 * 4) {
        float4 wv = *(const float4*)&We[idx];
        int k = idx >> 7;
        int col = idx & 127;
        int kk = k >> 5, qq = (k & 31) >> 3, j = k & 7;
        float wf[4] = {wv.x, wv.y, wv.z, wv.w};
        #pragma unroll
        for (int i = 0; i < 4; ++i) {
            int cc = (col + i) & 7, lc = (col + i) >> 3;
            int lane = (qq << 4) | lc;
            BHs[(((cc << 1) | kk) * 64 + lane) * 8 + j] = (short)rne16(wf[i]);
        }
    }
    if (threadIdx.x < 128) {
        int c = threadIdx.x & 7, lc = threadIdx.x >> 3;
        WA[lc * 9 + c] = make_float2(Web[threadIdx.x], Av[threadIdx.x]);
    }
    __syncthreads();

    const int l = threadIdx.x & 63;
    const int lanecol = l & 15;
    const int q = l >> 4;
    const int gbase = l & 48;
    const int wid = (blockIdx.x << 2) + (threadIdx.x >> 6);
    const int nW = gridDim.x << 2;
    const int NT = NE / 16;

    for (int tIdx = wid; tIdx < NT; tIdx += nW) {
        const int e0 = tIdx * 16;
        const int eb = e0 + (q << 2);

        int4 s4 = *(const int4*)&snd[eb];
        int4 r4 = *(const int4*)&rcv[eb];

        // --- issue all 8 h-row gathers (overlap with EF load below) ---
        bf16x8 hsv0 = *(const bf16x8*)(hbf + (size_t)s4.x * EMB + lanecol * 8);
        bf16x8 hrv0 = *(const bf16x8*)(hbf + (size_t)r4.x * EMB + lanecol * 8);
        bf16x8 hsv1 = *(const bf16x8*)(hbf + (size_t)s4.y * EMB + lanecol * 8);
        bf16x8 hrv1 = *(const bf16x8*)(hbf + (size_t)r4.y * EMB + lanecol * 8);
        bf16x8 hsv2 = *(const bf16x8*)(hbf + (size_t)s4.z * EMB + lanecol * 8);
        bf16x8 hrv2 = *(const bf16x8*)(hbf + (size_t)r4.z * EMB + lanecol * 8);
        bf16x8 hsv3 = *(const bf16x8*)(hbf + (size_t)s4.w * EMB + lanecol * 8);
        bf16x8 hrv3 = *(const bf16x8*)(hbf + (size_t)r4.w * EMB + lanecol * 8);

        // --- parallel bucket atomics (lanes 0-3 own one edge each) ---
        int ssel = (lanecol == 0) ? s4.x : (lanecol == 1) ? s4.y
                 : (lanecol == 2) ? s4.z : s4.w;
        int rsel = (lanecol == 0) ? r4.x : (lanecol == 1) ? r4.y
                 : (lanecol == 2) ? r4.z : r4.w;
        int pos4 = 0;
        if (lanecol < 4) {
            pos4 = atomicAdd(&cursor[rsel], 1);
            csr_snd[pos4] = ssel;
        }

        // --- EF load + immediate bf16 convert (floats transient) ---
        const float* ar = EF + (size_t)(e0 + lanecol) * ED + q * 8;
        bf16x8 ahi0, ahi1;
        {
            float4 a0 = *(const float4*)ar;
            float4 a1 = *(const float4*)(ar + 4);
            float4 a2 = *(const float4*)(ar + 32);
            float4 a3 = *(const float4*)(ar + 36);
            ahi0[0] = (short)rne16(a0.x); ahi0[1] = (short)rne16(a0.y);
            ahi0[2] = (short)rne16(a0.z); ahi0[3] = (short)rne16(a0.w);
            ahi0[4] = (short)rne16(a1.x); ahi0[5] = (short)rne16(a1.y);
            ahi0[6] = (short)rne16(a1.z); ahi0[7] = (short)rne16(a1.w);
            ahi1[0] = (short)rne16(a2.x); ahi1[1] = (short)rne16(a2.y);
            ahi1[2] = (short)rne16(a2.z); ahi1[3] = (short)rne16(a2.w);
            ahi1[4] = (short)rne16(a3.x); ahi1[5] = (short)rne16(a3.y);
            ahi1[6] = (short)rne16(a3.z); ahi1[7] = (short)rne16(a3.w);
        }

        // --- interleaved: per-chunk MFMA -> immediate epilogue slice ---
        float pp[4] = {0.f, 0.f, 0.f, 0.f};
        #pragma unroll
        for (int c = 0; c < 8; ++c) {
            bf16x8 b0 = *(bf16x8*)&BHs[(((c << 1) | 0) * 64 + l) * 8];
            bf16x8 b1 = *(bf16x8*)&BHs[(((c << 1) | 1) * 64 + l) * 8];
            f32x4 a4 = (f32x4){0.f, 0.f, 0.f, 0.f};
            a4 = __builtin_amdgcn_mfma_f32_16x16x32_bf16(ahi0, b0, a4, 0, 0, 0);
            a4 = __builtin_amdgcn_mfma_f32_16x16x32_bf16(ahi1, b1, a4, 0, 0, 0);
            float2 wa = WA[lanecol * 9 + c];
            pp[0] = fmaf(mishf(a4[0] + wa.x + bf2f(hsv0[c]) + bf2f(hrv0[c])), wa.y, pp[0]);
            pp[1] = fmaf(mishf(a4[1] + wa.x + bf2f(hsv1[c]) + bf2f(hrv1[c])), wa.y, pp[1]);
            pp[2] = fmaf(mishf(a4[2] + wa.x + bf2f(hsv2[c]) + bf2f(hrv2[c])), wa.y, pp[2]);
            pp[3] = fmaf(mishf(a4[3] + wa.x + bf2f(hsv3[c]) + bf2f(hrv3[c])), wa.y, pp[3]);
        }

        // --- reduce lane pairs, write ex ---
        #pragma unroll
        for (int r = 0; r < 4; ++r) {
            float pr = pp[r];
            pr += __shfl_xor(pr, 1, 16);
            const int pos = __shfl(pos4, gbase + r, 64);
            if ((lanecol & 1) == 0)
                ex_csr[(size_t)pos * NH + (lanecol >> 1)] = __expf(pr);
        }
    }
}

// --------- segmented aggregation: bf16 h, lane owns cols 2l,2l+1 -----------
__global__ __launch_bounds__(256) void k_agg(
    const short* __restrict__ hbf, const int* __restrict__ csr_snd,
    const float* __restrict__ ex_csr, const int* __restrict__ rowptr,
    float* __restrict__ out) {
    const int l = threadIdx.x & 63;
    const int node = blockIdx.x * 4 + (threadIdx.x >> 6);
    if (node >= NN) return;
    const int beg = rowptr[node], end = rowptr[node + 1];
    const int h = l >> 3;
    float a0 = 0.f, a1 = 0.f, den = 0.f;
    int j = beg;
    for (; j + 4 <= end; j += 4) {
        int s[4];
        float ex[4];
        unsigned hv[4];
        #pragma unroll
        for (int i = 0; i < 4; ++i) s[i] = csr_snd[j + i];
        #pragma unroll
        for (int i = 0; i < 4; ++i) ex[i] = ex_csr[(size_t)(j + i) * NH + h];
        #pragma unroll
        for (int i = 0; i < 4; ++i)
            hv[i] = *(const unsigned*)(hbf + (size_t)s[i] * EMB + 2 * l);
        #pragma unroll
        for (int i = 0; i < 4; ++i) {
            a0 = fmaf(ex[i], bf2f((short)(hv[i] & 0xFFFF)), a0);
            a1 = fmaf(ex[i], bf2f((short)(hv[i] >> 16)), a1);
            den += ex[i];
        }
    }
    for (; j < end; ++j) {
        float ex = ex_csr[(size_t)j * NH + h];
        unsigned hv = *(const unsigned*)(hbf + (size_t)csr_snd[j] * EMB + 2 * l);
        a0 = fmaf(ex, bf2f((short)(hv & 0xFFFF)), a0);
        a1 = fmaf(ex, bf2f((short)(hv >> 16)), a1);
        den += ex;
    }
    float rd = (end > beg) ? __builtin_amdgcn_rcpf(den) : 0.f;
    float2 o;
    o.x = a0 * rd;
    o.y = a1 * rd;
    *(float2*)&out[(size_t)node * EMB + 2 * l] = o;
}

extern "C" void kernel_launch(void* const* d_in, const int* in_sizes, int n_in,
                              void* d_out, int out_size, void* d_ws, size_t ws_size,
                              hipStream_t stream) {
    const float* X   = (const float*)d_in[0];
    const float* EF  = (const float*)d_in[1];
    const float* W   = (const float*)d_in[2];
    const float* Wb  = (const float*)d_in[3];
    const float* We  = (const float*)d_in[4];
    const float* Web = (const float*)d_in[5];
    const float* Av  = (const float*)d_in[6];
    const int* snd   = (const int*)d_in[7];
    const int* rcv   = (const int*)d_in[8];
    float* out = (float*)d_out;

    char* ws = (char*)d_ws;
    size_t off = 0;
    float* ex_csr = (float*)(ws + off); off += (size_t)NE * NH * 4;    // 25.6 MB
    int* csr_snd  = (int*)(ws + off);   off += (size_t)NE * 4;         // 3.2 MB
    int* rowptr   = (int*)(ws + off);   off += (size_t)(NN + 1) * 4;
    int* cursor   = (int*)(ws + off);   off += (size_t)NN * 4;
    int* part     = (int*)(ws + off);   off += 512;
    short* hbf    = (short*)(ws + off); off += (size_t)NN * EMB * 2;   // 12.8 MB
    int* cnt      = cursor;  // alias: consumed by k_part before k_fix2 rewrites

    hipMemsetAsync(cnt, 0, (size_t)NN * sizeof(int), stream);
    k_proj_hist<<<NPB + NHIST, 256, 0, stream>>>(X, W, Wb, hbf, rcv, cnt);
    k_part<<<NB, 512, 0, stream>>>(cnt, rowptr, part);
    k_fix2<<<NB, 512, 0, stream>>>(part, rowptr, cursor);
    k_edge_attn<<<2048, 256, 0, stream>>>(EF, We, Web, Av, hbf, snd, rcv,
                                          cursor, csr_snd, ex_csr);
    k_agg<<<(NN + 3) / 4, 256, 0, stream>>>(hbf, csr_snd, ex_csr, rowptr, out);
}